// Round 1
// baseline (262.827 us; speedup 1.0000x reference)
//
#include <hip/hip_runtime.h>

// out[l, i] = exp(l * A[i,i]) * B[i] * C[i] + D,  l in [0, L), i in [0, 256)
// L = 262144, n = 256. Output: 67.1M fp32 = 256 MiB -> HBM-write-bound.
//
// Layout: one wave (64 lanes x float4) writes exactly one 256-elem row.
// Block = 256 threads -> 4 rows per iteration. Grid = 2048 blocks, each
// owning 128 contiguous rows (262144 / 2048). 8 blocks/CU on 256 CUs.

#define SSM_N 256
#define SSM_L 262144
#define SSM_GRID 2048
#define SSM_BLOCK 256

__global__ __launch_bounds__(SSM_BLOCK) void SSMKernel_56770877718744_kernel(
    const float* __restrict__ A,   // (256, 256), only diagonal used
    const float* __restrict__ B,   // (256, 1)
    const float* __restrict__ C,   // (1, 256)
    const float* __restrict__ D,   // (1,)
    float* __restrict__ out)       // (L, 256)
{
    const int t = threadIdx.x;
    const int q = t & 63;          // quad index within row: columns 4q..4q+3
    const int c = q << 2;          // column base
    const int r = t >> 6;          // sub-row 0..3 within a 4-row group

    const float LOG2E = 1.4426950408889634f;

    // Per-column constants (loop-invariant; loads hit L1/L2, 256 values total).
    const float a0 = A[(size_t)(c + 0) * SSM_N + (c + 0)] * LOG2E;
    const float a1 = A[(size_t)(c + 1) * SSM_N + (c + 1)] * LOG2E;
    const float a2 = A[(size_t)(c + 2) * SSM_N + (c + 2)] * LOG2E;
    const float a3 = A[(size_t)(c + 3) * SSM_N + (c + 3)] * LOG2E;

    const float bc0 = B[c + 0] * C[c + 0];
    const float bc1 = B[c + 1] * C[c + 1];
    const float bc2 = B[c + 2] * C[c + 2];
    const float bc3 = B[c + 3] * C[c + 3];

    const float d = D[0];

    const int rows_per_block = SSM_L / SSM_GRID;   // 128
    const int row_lo = blockIdx.x * rows_per_block;
    const int row_hi = row_lo + rows_per_block;

    float4* __restrict__ o4 = (float4*)out;        // 64 float4 per row

    for (int l = row_lo + r; l < row_hi; l += 4) {
        const float lf = (float)l;                 // exact: l < 2^24
        float4 v;
        v.x = __builtin_amdgcn_exp2f(lf * a0) * bc0 + d;
        v.y = __builtin_amdgcn_exp2f(lf * a1) * bc1 + d;
        v.z = __builtin_amdgcn_exp2f(lf * a2) * bc2 + d;
        v.w = __builtin_amdgcn_exp2f(lf * a3) * bc3 + d;
        o4[(size_t)l * 64 + q] = v;
    }
}

extern "C" void kernel_launch(void* const* d_in, const int* in_sizes, int n_in,
                              void* d_out, int out_size, void* d_ws, size_t ws_size,
                              hipStream_t stream) {
    // Inputs (setup_inputs order): L (int scalar), A (256x256 f32),
    // B (256x1 f32), C (1x256 f32), D (1 f32).
    const float* A = (const float*)d_in[1];
    const float* B = (const float*)d_in[2];
    const float* C = (const float*)d_in[3];
    const float* D = (const float*)d_in[4];
    float* out = (float*)d_out;

    SSMKernel_56770877718744_kernel<<<SSM_GRID, SSM_BLOCK, 0, stream>>>(A, B, C, D, out);
}